// Round 1
// 186.327 us; speedup vs baseline: 1.0766x; 1.0766x over previous
//
#include <hip/hip_runtime.h>
#include <stdint.h>

// ---- problem constants ----
// z: [32][256][32][32] fp32, kappa:[1], codebook:[512][256], gumbel:[32768][512]
// out: z_to_decoder [32][256][32][32] (8388608) + loss + perplexity

typedef float v4f __attribute__((ext_vector_type(4)));
typedef short v8s __attribute__((ext_vector_type(8)));
typedef short v4s __attribute__((ext_vector_type(4)));

#define ZA_STR 264   // shorts; za row stride (16B aligned)
#define L2_STR 520   // shorts; er row stride (1040B = 65*16B, 16B aligned)

__device__ __forceinline__ uint16_t f2bf(float x) {
  uint32_t u = __float_as_uint(x);
  u = u + 0x7fffu + ((u >> 16) & 1u);   // round-to-nearest-even
  return (uint16_t)(u >> 16);
}

// ---- workspace layout (bytes) ----
// [0]       cbn2 bf16 [128K]  frag-permuted normalized codebook * kq (GEMM1 B)
// [262144]  cbt2 bf16 [128K]  frag-permuted transposed normalized codebook (GEMM2 B)
// [524288]  shadow fp32 [16][512]  avg_probs partial accumulators
// [557056]  scal fp32 [3]: {sum p*logp, sum z^2, sum er*(l2+mx)/Se}

// Single prep kernel: per-block row norms (reusing the loaded registers for the
// pack), kq folded into cbn2, plus shadow/scal zero-init. 128 blocks x 256.
__global__ __launch_bounds__(256) void vq_prep(const float* __restrict__ cb,
                                               const float* __restrict__ kappa,
                                               char* __restrict__ ws) {
  const int b = blockIdx.x, t = threadIdx.x;
  uint16_t* cbn2 = (uint16_t*)ws;
  uint16_t* cbt2 = (uint16_t*)(ws + 262144);
  float* shadow  = (float*)(ws + 524288);
  float* scal    = (float*)(ws + 557056);
  __shared__ float s_rn[8];

  // this block's 8 codes (b<64: cbn2 pack; b>=64: cbt2 pack — same code set)
  const int cbase = (b & 63) << 3;
  const int cl = t >> 5, lt = t & 31;       // code-local [0,8), lane-in-group [0,32)
  const float4 f0 = *(const float4*)(cb + (cbase + cl) * 256 + lt * 8);
  const float4 f1 = *(const float4*)(cb + (cbase + cl) * 256 + lt * 8 + 4);
  float s = f0.x*f0.x + f0.y*f0.y + f0.z*f0.z + f0.w*f0.w
          + f1.x*f1.x + f1.y*f1.y + f1.z*f1.z + f1.w*f1.w;
#pragma unroll
  for (int mm = 1; mm < 32; mm <<= 1) s += __shfl_xor(s, mm, 64);
  if (lt == 0) s_rn[cl] = 1.0f / sqrtf(s);
  __syncthreads();

  union { v8s v; uint16_t u[8]; } pk;
  if (b < 64) {
    const float kq = fminf(fmaxf(kappa[0], 1e-5f), 1e5f);
    const int code = cbase + cl, dch = lt;
    const float rn = s_rn[cl] * kq;         // kq folded into GEMM1 B
    pk.u[0] = f2bf(f0.x * rn); pk.u[1] = f2bf(f0.y * rn);
    pk.u[2] = f2bf(f0.z * rn); pk.u[3] = f2bf(f0.w * rn);
    pk.u[4] = f2bf(f1.x * rn); pk.u[5] = f2bf(f1.y * rn);
    pk.u[6] = f2bf(f1.z * rn); pk.u[7] = f2bf(f1.w * rn);
    const int w = code >> 7, ct = (code >> 4) & 7, mcol = code & 15;
    const int ks = dch >> 2, q3 = dch & 3;
    *(v8s*)(cbn2 + ((ks * 8 + ct) * 4 + w) * 512 + (q3 * 16 + mcol) * 8) = pk.v;
  } else {
    const int cgroup = b - 64, d = t;
#pragma unroll
    for (int j = 0; j < 8; j++) {
      const int c = cbase + j;
      pk.u[j] = f2bf(cb[c * 256 + d] * s_rn[j]);   // no kq here (GEMM2 B)
    }
    const int cc = cgroup >> 2, qq = cgroup & 3;   // k = cc*32 + qq*8 + j
    const int wd = d >> 6, nt = (d >> 4) & 3, md = d & 15;
    *(v8s*)(cbt2 + ((cc * 4 + nt) * 4 + wd) * 512 + (qq * 16 + md) * 8) = pk.v;
    if (t < 128) shadow[(cgroup << 7) + t] = 0.f;
    if (cgroup == 0 && t >= 128 && t < 131) scal[t - 128] = 0.f;
  }
}

__global__ __launch_bounds__(256, 4) void vq_main(const float* __restrict__ z,
                                                  const float* __restrict__ gum,
                                                  char* __restrict__ ws,
                                                  float* __restrict__ out) {
  __shared__ char s_A[33280];   // za short[32][264] -> er short[32][520] (in-place)
  __shared__ float s_pm[128], s_pS[128], s_pT[128];
  __shared__ float s_M[32], s_rS[32], s_kd[32], s_rSe[32], s_red[8];
  __shared__ float s_se[128], s_ce[128];   // per-wave row partials (fused pass2)
  __shared__ float s_col[512];             // column sums, atomics deferred to end

  const int t = threadIdx.x;
  const int w = t >> 6, lane = t & 63, q = lane >> 4, m = lane & 15;
  const int bi = blockIdx.x, b = bi >> 5, wh0 = (bi & 31) << 5;
  const int R0 = bi << 5;

  const uint16_t* cbn2 = (const uint16_t*)ws;
  const uint16_t* cbt2 = (const uint16_t*)(ws + 262144);
  float* shadow = (float*)(ws + 524288);
  float* scal   = (float*)(ws + 557056);

  uint16_t* za  = (uint16_t*)s_A;
  uint16_t* l2s = (uint16_t*)s_A;

  // ---------- staging: z -> LDS bf16 (A-layout) fused with sum(z^2) ----------
  {
    float zs = 0.f;
    const int whb = (t & 7) << 2, dT = t >> 3;
    const float* zb = z + ((size_t)b << 18) + wh0 + whb;
#pragma unroll
    for (int s = 0; s < 8; s++) {
      const int d = dT + (s << 5);
      const float4 v = *(const float4*)(zb + (d << 10));
      zs += v.x * v.x + v.y * v.y + v.z * v.z + v.w * v.w;
      za[(whb + 0) * ZA_STR + d] = f2bf(v.x);
      za[(whb + 1) * ZA_STR + d] = f2bf(v.y);
      za[(whb + 2) * ZA_STR + d] = f2bf(v.z);
      za[(whb + 3) * ZA_STR + d] = f2bf(v.w);
    }
#pragma unroll
    for (int mm = 1; mm < 64; mm <<= 1) zs += __shfl_xor(zs, mm, 64);
    if (lane == 0) s_red[w] = zs;
  }
  __syncthreads();  // B1
  if (t == 0) atomicAdd(&scal[1], s_red[0] + s_red[1] + s_red[2] + s_red[3]);

  // ---------- GEMM1: logits = z @ (kq*cbn)^T ; acc stays in registers ----------
  v4f acc0[8], acc1[8];
#pragma unroll
  for (int i = 0; i < 8; i++) { acc0[i] = (v4f)0.f; acc1[i] = (v4f)0.f; }
  {
    const uint16_t* bp  = cbn2 + (w << 9) + (lane << 3);
    const uint16_t* a0p = za + m * ZA_STR;
    const uint16_t* a1p = za + (m + 16) * ZA_STR;
#pragma unroll
    for (int ks = 0; ks < 8; ks++) {
      const v8s a0 = *(const v8s*)(a0p + (ks << 5) + (q << 3));
      const v8s a1 = *(const v8s*)(a1p + (ks << 5) + (q << 3));
#pragma unroll
      for (int ct = 0; ct < 8; ct++) {
        const v8s bf = *(const v8s*)(bp + (((ks << 3) + ct) << 11));
        acc0[ct] = __builtin_amdgcn_mfma_f32_16x16x32_bf16(a0, bf, acc0[ct], 0, 0, 0);
        acc1[ct] = __builtin_amdgcn_mfma_f32_16x16x32_bf16(a1, bf, acc1[ct], 0, 0, 0);
      }
    }
  }

  // ---------- per-wave per-row softmax stats from accumulators ----------
  {
    auto stats_half = [&](v4f (&acc)[8], int half) {
#pragma unroll
      for (int reg = 0; reg < 4; reg++) {
        float mx = -1e30f;
#pragma unroll
        for (int ct = 0; ct < 8; ct++) mx = fmaxf(mx, acc[ct][reg]);
#pragma unroll
        for (int mm = 1; mm < 16; mm <<= 1) mx = fmaxf(mx, __shfl_xor(mx, mm, 64));
        float S = 0.f, T = 0.f;
#pragma unroll
        for (int ct = 0; ct < 8; ct++) {
          const float d = acc[ct][reg] - mx;
          const float e = __expf(d);
          S += e; T += d * e;
        }
#pragma unroll
        for (int mm = 1; mm < 16; mm <<= 1) { S += __shfl_xor(S, mm, 64); T += __shfl_xor(T, mm, 64); }
        if (m == 0) {
          const int r = half * 16 + q * 4 + reg;
          s_pm[(w << 5) + r] = mx; s_pS[(w << 5) + r] = S; s_pT[(w << 5) + r] = T;
        }
      }
    };
    stats_half(acc0, 0);
    stats_half(acc1, 1);
  }

  // gumbel prefetch for fused pass2, fragment layout: rows R0 + h*16 + q*4 + rg,
  // cols (w<<7) + ct*16 + m. Groups g = h*4+rg; preload g=0,1 here so the loads
  // are in flight across the B2/B3 merge waits.
  const float* gT = gum + (((size_t)R0 + (q << 2)) << 9) + (w << 7) + m;
  float gb[2][8];
#pragma unroll
  for (int ct = 0; ct < 8; ct++) gb[0][ct] = gT[ct << 4];
#pragma unroll
  for (int ct = 0; ct < 8; ct++) gb[1][ct] = gT[512 + (ct << 4)];

  __syncthreads();  // B2
  if (t < 32) {  // merge 4 wave-partials per row (online-softmax merge)
    float M = s_pm[t];
    M = fmaxf(M, s_pm[32 + t]); M = fmaxf(M, s_pm[64 + t]); M = fmaxf(M, s_pm[96 + t]);
    float S = 0.f, T = 0.f;
#pragma unroll
    for (int ww = 0; ww < 4; ww++) {
      const float dm = s_pm[ww * 32 + t] - M;
      const float al = __expf(dm);
      S += s_pS[ww * 32 + t] * al;
      T += (s_pT[ww * 32 + t] + dm * s_pS[ww * 32 + t]) * al;
    }
    const float rS = 1.0f / S;
    s_M[t] = M; s_rS[t] = rS; s_kd[t] = T * rS - __logf(S);
  }
  __syncthreads();  // B3

  // ---------- fused pass2 + gumbel transform: p colsums, er -> LDS bf16 ----------
  // er = (e/L)^2 = exp((l2+g)/T), T=0.5. log(e)=d is in-register: no __logf(e),
  // no e round-trip through LDS, no separate transform phase.
  {
    const int c0 = w << 7;
    float colacc[8];
#pragma unroll
    for (int i = 0; i < 8; i++) colacc[i] = 0.f;
#pragma unroll
    for (int g = 0; g < 8; g++) {
      const int h = g >> 2, rg = g & 3;
      const int r = (h << 4) + (q << 2) + rg;
      const float Mr = s_M[r], rSr = s_rS[r];
      uint16_t* lrow = l2s + r * L2_STR + c0 + m;
      float se = 0.f, ce = 0.f;
#pragma unroll
      for (int ct = 0; ct < 8; ct++) {
        const float a = h ? acc1[ct][rg] : acc0[ct][rg];
        const float d = fmaxf(a - Mr, -50.0f);
        const float e = __expf(d);
        colacc[ct] += e * rSr;
        const float L = 1e-10f - __logf(gb[g & 1][ct] + 1e-10f);
        const float f = __fdividef(e, L);
        const float er = f * f;
        se += er;
        ce += er * (d + Mr);                  // er * raw_logit (analytic z.zq)
        lrow[ct << 4] = f2bf(er);
      }
      if (g < 6) {   // rolling prefetch of group g+2 (buffer just consumed)
        const int g2 = g + 2;
        const int off = (((g2 >> 2) << 4) + (g2 & 3)) << 9;
#pragma unroll
        for (int ct = 0; ct < 8; ct++) gb[g & 1][ct] = gT[off + (ct << 4)];
      }
#pragma unroll
      for (int mm = 1; mm < 16; mm <<= 1) {
        se += __shfl_xor(se, mm, 64);
        ce += __shfl_xor(ce, mm, 64);
      }
      if (m == 0) { s_se[(w << 5) + r] = se; s_ce[(w << 5) + r] = ce; }
    }
    // stash column partials in LDS; global atomics deferred past the epilogue
#pragma unroll
    for (int i = 0; i < 8; i++) {
      colacc[i] += __shfl_xor(colacc[i], 16, 64);
      colacc[i] += __shfl_xor(colacc[i], 32, 64);
    }
    if (q == 0) {
#pragma unroll
      for (int i = 0; i < 8; i++) s_col[c0 + (i << 4) + m] = colacc[i];
    }
  }
  __syncthreads();  // B4 — er + row/col partials visible

  // merge se/ce across waves (overlaps other waves' GEMM2)
  if (t < 32) {
    const float se = s_se[t] + s_se[32 + t] + s_se[64 + t] + s_se[96 + t];
    const float ce = s_ce[t] + s_ce[32 + t] + s_ce[64 + t] + s_ce[96 + t];
    s_rSe[t] = 1.0f / se;
    float cr = ce / se;
#pragma unroll
    for (int mm = 1; mm < 32; mm <<= 1) cr += __shfl_xor(cr, mm, 64);
    if (t == 0) atomicAdd(&scal[2], cr);
  }

  // ---------- GEMM2: zq = (er @ cbn) / Se — 128 MFMA, no barriers ----------
  v4f acc2a[4], acc2b[4];
#pragma unroll
  for (int i = 0; i < 4; i++) { acc2a[i] = (v4f)0.f; acc2b[i] = (v4f)0.f; }
  {
    const uint16_t* a0p = l2s + m * L2_STR;
    const uint16_t* a1p = l2s + (m + 16) * L2_STR;
#pragma unroll
    for (int cc = 0; cc < 16; cc++) {
      const v8s a0 = *(const v8s*)(a0p + (cc << 5) + (q << 3));
      const v8s a1 = *(const v8s*)(a1p + (cc << 5) + (q << 3));
      const uint16_t* bp2 = cbt2 + (cc << 13) + (w << 9) + (lane << 3);
#pragma unroll
      for (int nt = 0; nt < 4; nt++) {
        const v8s bf = *(const v8s*)(bp2 + (nt << 11));
        acc2a[nt] = __builtin_amdgcn_mfma_f32_16x16x32_bf16(a0, bf, acc2a[nt], 0, 0, 0);
        acc2b[nt] = __builtin_amdgcn_mfma_f32_16x16x32_bf16(a1, bf, acc2b[nt], 0, 0, 0);
      }
    }
  }
  __syncthreads();  // B5 — s_rSe visible for epilogue

  // ---------- epilogue: direct strided stores (write-amp is free at 14% HBM) ----------
  {
    float* ob = out + ((size_t)b << 18) + wh0;
    const int d0 = w << 6;
    float rsA[4], rsB[4];
#pragma unroll
    for (int reg = 0; reg < 4; reg++) {
      rsA[reg] = s_rSe[q * 4 + reg];
      rsB[reg] = s_rSe[16 + q * 4 + reg];
    }
#pragma unroll
    for (int nt = 0; nt < 4; nt++) {
      const int d = d0 + (nt << 4) + m;
#pragma unroll
      for (int reg = 0; reg < 4; reg++) {
        ob[(d << 10) + q * 4 + reg]      = acc2a[nt][reg] * rsA[reg];
        ob[(d << 10) + 16 + q * 4 + reg] = acc2b[nt][reg] * rsB[reg];
      }
    }
  }

  // ---------- deferred global atomics: no barrier after, drain at endpgm ----------
  {
    float* sh = shadow + ((bi & 15) << 9);
    atomicAdd(&sh[t], s_col[t]);
    atomicAdd(&sh[256 + t], s_col[256 + t]);
    if (w == 0) {  // kld_discrete partial: one atomic per block
      float kd = s_kd[lane & 31];
#pragma unroll
      for (int mm = 1; mm < 64; mm <<= 1) kd += __shfl_xor(kd, mm, 64);
      if (lane == 0) atomicAdd(&scal[0], 0.5f * kd);
    }
  }
}

__global__ __launch_bounds__(512) void vq_final(const float* __restrict__ kappa,
                                                char* __restrict__ ws,
                                                float* __restrict__ out) {
  __shared__ float red[8];
  const int t = threadIdx.x;
  const float* shadow = (const float*)(ws + 524288);
  const float* scal   = (const float*)(ws + 557056);
  float s = 0.f;
#pragma unroll
  for (int j = 0; j < 16; j++) s += shadow[(j << 9) + t];
  float avg = fmaxf(s * (1.0f / 32768.0f), 1e-10f);
  float term = avg * __logf(avg + 1e-10f);
#pragma unroll
  for (int mm = 1; mm < 64; mm <<= 1) term += __shfl_xor(term, mm, 64);
  if ((t & 63) == 0) red[t >> 6] = term;
  __syncthreads();
  if (t == 0) {
    float H = 0.f;
#pragma unroll
    for (int i = 0; i < 8; i++) H += red[i];
    const float perpl = __expf(-H);
    const float kq = fminf(fmaxf(kappa[0], 1e-5f), 1e5f);
    const float loss = (scal[0] + kq * scal[1] - scal[2]) * (1.0f / 32.0f);
    out[8388608] = loss;
    out[8388609] = perpl;
  }
}

extern "C" void kernel_launch(void* const* d_in, const int* in_sizes, int n_in,
                              void* d_out, int out_size, void* d_ws, size_t ws_size,
                              hipStream_t stream) {
  const float* z     = (const float*)d_in[0];
  const float* kappa = (const float*)d_in[1];
  const float* cb    = (const float*)d_in[2];
  const float* gum   = (const float*)d_in[3];
  char* ws = (char*)d_ws;
  float* out = (float*)d_out;
  hipLaunchKernelGGL(vq_prep,  dim3(128),  dim3(256), 0, stream, cb, kappa, ws);
  hipLaunchKernelGGL(vq_main,  dim3(1024), dim3(256), 0, stream, z, gum, ws, out);
  hipLaunchKernelGGL(vq_final, dim3(1),    dim3(512), 0, stream, kappa, ws, out);
}